// Round 7
// baseline (1416.743 us; speedup 1.0000x reference)
//
#include <hip/hip_runtime.h>
#include <hip/hip_cooperative_groups.h>
#include <math.h>

namespace cg = cooperative_groups;

#define Bdim 16
#define Mdim 4096
#define Tdim 4
#define Ddim 256
#define Vdim 40000
#define CONVMAX 512

#define NT 256

// dot (D = tab . uf) tiling
#define DOT_VT 64
#define DOT_TILES (Vdim / DOT_VT)               // 625
#define DOT_KC 64
#define HD_JPB 32
#define HD_TILES (Bdim * (CONVMAX / HD_JPB))    // 256
// wsum tiling
#define WS_VT 50
#define WS_TILES (Vdim / WS_VT)                 // 800
#define WH_JPB 64
#define WH_TILES (Bdim * (CONVMAX / WH_JPB))    // 128
// att tiling
#define MT 64
#define ATT_TILES (Bdim * (Mdim / MT))          // 1024

typedef float f32x4 __attribute__((ext_vector_type(4)));
static __device__ inline void nt_store4(float* p, float4 v) {
    f32x4 x = {v.x, v.y, v.z, v.w};
    __builtin_nontemporal_store(x, (f32x4*)p);
}
static __device__ inline void nt_store1(float* p, float v) {
    __builtin_nontemporal_store(v, p);
}

// ---------------------------------------------------------------------------
// One cooperative kernel: 3 hops of {dot -> logit(+max/sum partials, +zero)
// -> scatter -> wsum -> ufred}, final hop replaces scatter/wsum with the
// mandatory out_m gather (att) + attred.  13 grid.sync()s total.
// All phase bodies are the round-6 verified kernels, grid-strided.
// ---------------------------------------------------------------------------
__global__ __launch_bounds__(NT, 4) void fused_kernel(
    const int* __restrict__ story, const int* __restrict__ kb_len,
    const int* __restrict__ conv_len, const float* __restrict__ hist,
    const float* __restrict__ qv, const float* __restrict__ gp,
    const float* __restrict__ C_emb,
    float* __restrict__ out_psoft, float* __restrict__ out_logits,
    float* __restrict__ uf, float* __restrict__ out_m,
    float* __restrict__ D, float* __restrict__ w,
    float* __restrict__ Hdot, float* __restrict__ pwin,
    float* __restrict__ logits, float* __restrict__ blockmax,
    float* __restrict__ blocksum, float* __restrict__ partial,
    float* __restrict__ histpart, float* __restrict__ attpart)
{
    cg::grid_group grid = cg::this_grid();
    const int nb = gridDim.x;
    const int tid = threadIdx.x;
    const int wave = tid >> 6, lane = tid & 63;
    const int d4 = lane * 4;
    __shared__ __align__(16) float smem[80 * (DOT_KC + 4)];   // 21760 B

    const size_t TAB = (size_t)Vdim * Ddim;

    for (int h = 0; h < 3; ++h) {
        const float* qt = C_emb + (size_t)h * TAB;        // logit-side table
        const float* vt = C_emb + (size_t)(h + 1) * TAB;  // value-side table
        const float* ufsrc = (h == 0) ? qv : uf;
        float* lgbuf = (h == 2) ? out_logits : logits;

        // ================= P1: DOT  (D[v,b] = qt[v,:].ufsrc[b,:]; Hdot) ====
        for (int it = blockIdx.x; it < DOT_TILES + HD_TILES; it += nb) {
            if (it < DOT_TILES) {
                float (*tl)[DOT_KC + 4]  = (float (*)[DOT_KC + 4])smem;
                float (*ufl)[DOT_KC + 4] = (float (*)[DOT_KC + 4])(smem + DOT_VT * (DOT_KC + 4));
                const int v0 = it * DOT_VT;
                const int vA = (tid >> 3) * 2, vB = vA + 1;
                const int bA = (tid & 7) * 2,  bB = bA + 1;
                float aA0 = 0.f, aA1 = 0.f, aB0 = 0.f, aB1 = 0.f;
                for (int kc = 0; kc < Ddim; kc += DOT_KC) {
                    __syncthreads();
#pragma unroll
                    for (int i = 0; i < 4; ++i) {
                        int idx = tid + i * NT;
                        int r = idx >> 4, c4 = idx & 15;
                        *(float4*)(&tl[r][c4 * 4]) =
                            *(const float4*)(qt + (size_t)(v0 + r) * Ddim + kc + c4 * 4);
                    }
                    {
                        int r = tid >> 4, c4 = tid & 15;
                        *(float4*)(&ufl[r][c4 * 4]) =
                            *(const float4*)(ufsrc + (size_t)r * Ddim + kc + c4 * 4);
                    }
                    __syncthreads();
#pragma unroll
                    for (int k4 = 0; k4 < DOT_KC / 4; ++k4) {
                        const float4 a  = *(const float4*)(&tl[vA][k4 * 4]);
                        const float4 c  = *(const float4*)(&tl[vB][k4 * 4]);
                        const float4 u0 = *(const float4*)(&ufl[bA][k4 * 4]);
                        const float4 u1 = *(const float4*)(&ufl[bB][k4 * 4]);
                        aA0 += a.x*u0.x + a.y*u0.y + a.z*u0.z + a.w*u0.w;
                        aA1 += a.x*u1.x + a.y*u1.y + a.z*u1.z + a.w*u1.w;
                        aB0 += c.x*u0.x + c.y*u0.y + c.z*u0.z + c.w*u0.w;
                        aB1 += c.x*u1.x + c.y*u1.y + c.z*u1.z + c.w*u1.w;
                    }
                }
                size_t base = (size_t)(v0 + vA) * Bdim;
                D[base + bA] = aA0;  D[base + bB] = aA1;
                D[base + Bdim + bA] = aB0;  D[base + Bdim + bB] = aB1;
            } else {
                int r = it - DOT_TILES;
                int b = r >> 4, j0 = (r & 15) * HD_JPB;
                const float4 u = *(const float4*)(ufsrc + (size_t)b * Ddim + d4);
                for (int j = j0 + wave; j < j0 + HD_JPB; j += 4) {
                    const float4 hv = *(const float4*)(hist + ((size_t)b * CONVMAX + j) * Ddim + d4);
                    float s = hv.x*u.x + hv.y*u.y + hv.z*u.z + hv.w*u.w;
#pragma unroll
                    for (int off = 32; off > 0; off >>= 1) s += __shfl_xor(s, off, 64);
                    if (lane == 0) Hdot[b * CONVMAX + j] = s;
                }
            }
        }
        grid.sync();

        // ================= P2: LOGIT + blockmax/blocksum + zero w,pwin =====
        {
            const int nzero = (h < 2) ? (Vdim * Bdim / 1024 + Bdim * CONVMAX / 1024) : 0; // 633
            for (int it = blockIdx.x; it < 256 + nzero; it += nb) {
                if (it < 256) {
                    int row = it * NT + tid;
                    int b = row >> 12, m = row & (Mdim - 1);
                    const int4 st = *(const int4*)(story + (size_t)row * Tdim);
                    float l = D[st.x*Bdim + b] + D[st.y*Bdim + b] + D[st.z*Bdim + b] + D[st.w*Bdim + b];
                    unsigned j = (unsigned)(m - kb_len[b]);
                    if (j < (unsigned)conv_len[b]) l += Hdot[b * CONVMAX + j];
                    l *= gp[row];
                    lgbuf[row] = l;
                    float* sh = smem;
                    __syncthreads();
                    sh[tid] = l; __syncthreads();
                    for (int s = 128; s > 0; s >>= 1) { if (tid < s) sh[tid] = fmaxf(sh[tid], sh[tid + s]); __syncthreads(); }
                    float bm = sh[0]; __syncthreads();
                    sh[tid] = expf(l - bm); __syncthreads();
                    for (int s = 128; s > 0; s >>= 1) { if (tid < s) sh[tid] += sh[tid + s]; __syncthreads(); }
                    if (tid == 0) { blockmax[it] = bm; blocksum[it] = sh[0]; }
                } else if (it < 256 + Vdim * Bdim / 1024) {
                    int r = it - 256;
                    *(float4*)(w + (size_t)r * 1024 + tid * 4) = make_float4(0.f, 0.f, 0.f, 0.f);
                } else {
                    int r = it - (256 + Vdim * Bdim / 1024);
                    *(float4*)(pwin + (size_t)r * 1024 + tid * 4) = make_float4(0.f, 0.f, 0.f, 0.f);
                }
            }
        }
        grid.sync();

        if (h < 2) {
            // ================= P3: SCATTER =================
            for (int it = blockIdx.x; it < 256; it += nb) {
                int b = it >> 4;
                float M = -INFINITY;
#pragma unroll
                for (int jj = 0; jj < 16; ++jj) M = fmaxf(M, blockmax[b * 16 + jj]);
                float S = 0.f;
#pragma unroll
                for (int jj = 0; jj < 16; ++jj) S += blocksum[b * 16 + jj] * expf(blockmax[b * 16 + jj] - M);
                float rs = 1.0f / S;
                int row = it * NT + tid;
                int m = row & (Mdim - 1);
                float p = expf(logits[row] - M) * rs * gp[row];
                const int4 st = *(const int4*)(story + (size_t)row * Tdim);
                atomicAdd(&w[st.x * Bdim + b], p);
                atomicAdd(&w[st.y * Bdim + b], p);
                atomicAdd(&w[st.z * Bdim + b], p);
                atomicAdd(&w[st.w * Bdim + b], p);
                unsigned j = (unsigned)(m - kb_len[b]);
                if (j < (unsigned)conv_len[b]) pwin[b * CONVMAX + j] = p;
            }
            grid.sync();

            // ================= P4: WSUM (partials, no atomics) =============
            for (int it = blockIdx.x; it < WS_TILES + WH_TILES; it += nb) {
                if (it < WS_TILES) {
                    float* wsl = smem;                       // 800 floats
                    int v0 = it * WS_VT;
                    __syncthreads();
                    for (int i = tid; i < WS_VT * Bdim; i += NT) wsl[i] = w[(size_t)v0 * Bdim + i];
                    __syncthreads();
                    int b0 = wave * 4;
                    float4 a0 = make_float4(0.f,0.f,0.f,0.f), a1 = a0, a2 = a0, a3 = a0;
                    for (int v = 0; v < WS_VT; ++v) {
                        const float4 t = *(const float4*)(vt + (size_t)(v0 + v) * Ddim + d4);
                        float w0 = wsl[v * Bdim + b0],     w1 = wsl[v * Bdim + b0 + 1];
                        float w2 = wsl[v * Bdim + b0 + 2], w3 = wsl[v * Bdim + b0 + 3];
                        a0.x += w0*t.x; a0.y += w0*t.y; a0.z += w0*t.z; a0.w += w0*t.w;
                        a1.x += w1*t.x; a1.y += w1*t.y; a1.z += w1*t.z; a1.w += w1*t.w;
                        a2.x += w2*t.x; a2.y += w2*t.y; a2.z += w2*t.z; a2.w += w2*t.w;
                        a3.x += w3*t.x; a3.y += w3*t.y; a3.z += w3*t.z; a3.w += w3*t.w;
                    }
                    *(float4*)(&partial[((size_t)(b0 + 0) * WS_TILES + it) * Ddim + d4]) = a0;
                    *(float4*)(&partial[((size_t)(b0 + 1) * WS_TILES + it) * Ddim + d4]) = a1;
                    *(float4*)(&partial[((size_t)(b0 + 2) * WS_TILES + it) * Ddim + d4]) = a2;
                    *(float4*)(&partial[((size_t)(b0 + 3) * WS_TILES + it) * Ddim + d4]) = a3;
                } else {
                    int r = it - WS_TILES;
                    int b = r >> 3, j0 = (r & 7) * WH_JPB;
                    float* sp = smem;
                    __syncthreads();
                    if (tid < WH_JPB) sp[tid] = pwin[b * CONVMAX + j0 + tid];
                    __syncthreads();
                    float acc = 0.f;
                    const float* hb = hist + ((size_t)b * CONVMAX + j0) * Ddim + tid;
#pragma unroll 8
                    for (int j = 0; j < WH_JPB; ++j) acc += sp[j] * hb[(size_t)j * Ddim];
                    histpart[((size_t)b * 8 + (r & 7)) * Ddim + tid] = acc;
                }
            }
            grid.sync();

            // ================= P5: UFRED  (uf = base + partials) ===========
            for (int it = blockIdx.x; it < Bdim; it += nb) {
                int b = it;
                float4 acc = make_float4(0.f, 0.f, 0.f, 0.f);
                for (int s = wave; s < WS_TILES; s += 4) {
                    const float4 p4 = *(const float4*)(&partial[((size_t)b * WS_TILES + s) * Ddim + d4]);
                    acc.x += p4.x; acc.y += p4.y; acc.z += p4.z; acc.w += p4.w;
                }
                if (wave == 0) {
#pragma unroll
                    for (int c = 0; c < 8; ++c) {
                        const float4 hp = *(const float4*)(&histpart[((size_t)b * 8 + c) * Ddim + d4]);
                        acc.x += hp.x; acc.y += hp.y; acc.z += hp.z; acc.w += hp.w;
                    }
                }
                float4* red = (float4*)smem;
                __syncthreads();
                red[wave * 64 + lane] = acc;
                __syncthreads();
                if (wave == 0) {
                    float4 r0 = red[lane], r1 = red[64 + lane], r2 = red[128 + lane], r3 = red[192 + lane];
                    const float* basep = (h == 0) ? qv : uf;
                    float4 bv = *(const float4*)(basep + (size_t)b * Ddim + d4);
                    bv.x += r0.x + r1.x + r2.x + r3.x;
                    bv.y += r0.y + r1.y + r2.y + r3.y;
                    bv.z += r0.z + r1.z + r2.z + r3.z;
                    bv.w += r0.w + r1.w + r2.w + r3.w;
                    *(float4*)(uf + (size_t)b * Ddim + d4) = bv;
                }
            }
            grid.sync();
        } else {
            // ================= P3': ATT (mandatory out_m gather) ===========
            for (int it = blockIdx.x; it < ATT_TILES; it += nb) {
                int b = it >> 6, m0 = (it & 63) * MT;
                float* prob = smem;
                float4* red = (float4*)(smem + 64);
                __syncthreads();
                if (tid < MT) {
                    float M = -INFINITY;
#pragma unroll
                    for (int jj = 0; jj < 16; ++jj) M = fmaxf(M, blockmax[b * 16 + jj]);
                    float S = 0.f;
#pragma unroll
                    for (int jj = 0; jj < 16; ++jj) S += blocksum[b * 16 + jj] * expf(blockmax[b * 16 + jj] - M);
                    float rs = 1.0f / S;
                    size_t row = (size_t)b * Mdim + m0 + tid;
                    float pn = expf(out_logits[row] - M) * rs;
                    nt_store1(out_psoft + row, pn);
                    prob[tid] = pn * gp[row];
                }
                __syncthreads();
                int kb = kb_len[b], cl = conv_len[b];
                float4 acc = make_float4(0.f, 0.f, 0.f, 0.f);
                for (int mm = wave; mm < MT; mm += 4) {
                    int m = m0 + mm;
                    size_t row = (size_t)b * Mdim + m;
                    const int* st = story + row * Tdim;
                    float4 v = make_float4(0.f, 0.f, 0.f, 0.f);
#pragma unroll
                    for (int t = 0; t < Tdim; ++t) {
                        const float4 tv = *(const float4*)(vt + (size_t)st[t] * Ddim + d4);
                        v.x += tv.x; v.y += tv.y; v.z += tv.z; v.w += tv.w;
                    }
                    if (m >= kb && m < kb + cl) {
                        const float4 hv = *(const float4*)(hist + ((size_t)b * CONVMAX + (m - kb)) * Ddim + d4);
                        v.x += hv.x; v.y += hv.y; v.z += hv.z; v.w += hv.w;
                    }
                    nt_store4(out_m + row * Ddim + d4, v);
                    float p = prob[mm];
                    acc.x += p * v.x; acc.y += p * v.y; acc.z += p * v.z; acc.w += p * v.w;
                }
                red[wave * 64 + lane] = acc;
                __syncthreads();
                if (wave == 0) {
                    float4 a0 = red[lane], a1 = red[64 + lane], a2 = red[128 + lane], a3 = red[192 + lane];
                    float4 t4;
                    t4.x = a0.x + a1.x + a2.x + a3.x;
                    t4.y = a0.y + a1.y + a2.y + a3.y;
                    t4.z = a0.z + a1.z + a2.z + a3.z;
                    t4.w = a0.w + a1.w + a2.w + a3.w;
                    *(float4*)(&attpart[((size_t)b * 64 + (it & 63)) * Ddim + d4]) = t4;
                }
            }
            grid.sync();

            // ================= P4': ATTRED  (uf += att contribution) =======
            for (int it = blockIdx.x; it < Bdim; it += nb) {
                int b = it;
                float4 acc = make_float4(0.f, 0.f, 0.f, 0.f);
                for (int c = wave; c < 64; c += 4) {
                    const float4 p4 = *(const float4*)(&attpart[((size_t)b * 64 + c) * Ddim + d4]);
                    acc.x += p4.x; acc.y += p4.y; acc.z += p4.z; acc.w += p4.w;
                }
                float4* red = (float4*)smem;
                __syncthreads();
                red[wave * 64 + lane] = acc;
                __syncthreads();
                if (wave == 0) {
                    float4 r0 = red[lane], r1 = red[64 + lane], r2 = red[128 + lane], r3 = red[192 + lane];
                    float* dst = uf + (size_t)b * Ddim + d4;
                    float4 cur = *(const float4*)dst;
                    cur.x += r0.x + r1.x + r2.x + r3.x;
                    cur.y += r0.y + r1.y + r2.y + r3.y;
                    cur.z += r0.z + r1.z + r2.z + r3.z;
                    cur.w += r0.w + r1.w + r2.w + r3.w;
                    *(float4*)dst = cur;
                }
            }
        }
    }
}

extern "C" void kernel_launch(void* const* d_in, const int* in_sizes, int n_in,
                              void* d_out, int out_size, void* d_ws, size_t ws_size,
                              hipStream_t stream) {
    const int*   story        = (const int*)d_in[0];
    const int*   kb_len       = (const int*)d_in[1];
    const int*   conv_len     = (const int*)d_in[2];
    // d_in[3] (query), d_in[8..11] (Tg_w, Tg_b, FW_w, FW_b): dead w.r.t. outputs
    const float* hist         = (const float*)d_in[4];
    const float* query_vector = (const float*)d_in[5];
    const float* gp           = (const float*)d_in[6];
    const float* C_emb        = (const float*)d_in[7];

    float* out        = (float*)d_out;
    float* out_psoft  = out;                                   // B*M
    float* out_logits = out + (size_t)Bdim * Mdim;             // B*M
    float* out_uf     = out + 2 * (size_t)Bdim * Mdim;         // B*D
    float* out_m      = out + 2 * (size_t)Bdim * Mdim + (size_t)Bdim * Ddim; // B*M*D

    float* wsp = (float*)d_ws;
    float* D        = wsp;                                     // V*B
    float* w        = D + (size_t)Vdim * Bdim;                 // V*B
    float* Hdot     = w + (size_t)Vdim * Bdim;                 // B*CONVMAX
    float* pwin     = Hdot + (size_t)Bdim * CONVMAX;           // B*CONVMAX
    float* logits   = pwin + (size_t)Bdim * CONVMAX;           // B*M
    float* blockmax = logits + (size_t)Bdim * Mdim;            // 256
    float* blocksum = blockmax + 256;                          // 256
    float* partial  = blocksum + 256;                          // B*800*D
    float* histpart = partial + (size_t)Bdim * WS_TILES * Ddim; // B*8*D
    float* attpart  = histpart + (size_t)Bdim * 8 * Ddim;      // B*64*D

    static int coopGrid = 0;
    if (coopGrid == 0) {
        int nblk = 0;
        hipOccupancyMaxActiveBlocksPerMultiprocessor(&nblk, fused_kernel, NT, 0);
        if (nblk < 1) nblk = 1;
        hipDeviceProp_t prop;
        int dev = 0;
        hipGetDevice(&dev);
        hipGetDeviceProperties(&prop, dev);
        long cap = (long)nblk * prop.multiProcessorCount;
        coopGrid = (int)((cap < 1024) ? cap : 1024);
    }

    void* args[] = {
        (void*)&story, (void*)&kb_len, (void*)&conv_len, (void*)&hist,
        (void*)&query_vector, (void*)&gp, (void*)&C_emb,
        (void*)&out_psoft, (void*)&out_logits, (void*)&out_uf, (void*)&out_m,
        (void*)&D, (void*)&w, (void*)&Hdot, (void*)&pwin, (void*)&logits,
        (void*)&blockmax, (void*)&blocksum, (void*)&partial, (void*)&histpart,
        (void*)&attpart
    };
    hipLaunchCooperativeKernel((void*)fused_kernel, dim3(coopGrid), dim3(NT),
                               args, 0, stream);
}

// Round 8
// 419.353 us; speedup vs baseline: 3.3784x; 3.3784x over previous
//
#include <hip/hip_runtime.h>
#include <math.h>

#define Bdim 16
#define Mdim 4096
#define Tdim 4
#define Ddim 256
#define Vdim 40000
#define CONVMAX 512

// dot (D = tab . uf) tiling
#define DOT_VT 64
#define DOT_TILES (Vdim / DOT_VT)               // 625
#define DOT_KC 64
#define HD_JPB 32
#define HD_TILES (Bdim * (CONVMAX / HD_JPB))    // 256
// logit tiling
#define LG_TILES (Bdim * Mdim / 256)            // 256  (16 per b)
#define ZW_BLOCKS (Vdim * Bdim / 1024)          // 625
#define PW_BLOCKS (Bdim * CONVMAX / 1024)       // 8
// wsum tiling
#define WS_VT 50
#define WS_TILES (Vdim / WS_VT)                 // 800
#define WH_JPB 64
#define WH_TILES (Bdim * (CONVMAX / WH_JPB))    // 128
// reduce tiling
#define UF_CH 8                                  // tile-chunks per b
#define UF_PER (WS_TILES / UF_CH)                // 100
// att tiling
#define MT 32
#define ATT_CH (Mdim / MT)                       // 128
#define ATT_TILES (Bdim * ATT_CH)                // 2048

typedef float f32x4 __attribute__((ext_vector_type(4)));
static __device__ inline void nt_store4(float* p, float4 v) {
    f32x4 x = {v.x, v.y, v.z, v.w};
    __builtin_nontemporal_store(x, (f32x4*)p);
}
static __device__ inline void nt_store1(float* p, float v) {
    __builtin_nontemporal_store(v, p);
}

// combine per-b softmax partials (16 blocks of 256 rows each)
static __device__ inline void combine_stats(const float* __restrict__ blockmax,
                                            const float* __restrict__ blocksum,
                                            int b, float* M_out, float* rs_out) {
    float M = -INFINITY;
#pragma unroll
    for (int jj = 0; jj < 16; ++jj) M = fmaxf(M, blockmax[b * 16 + jj]);
    float S = 0.f;
#pragma unroll
    for (int jj = 0; jj < 16; ++jj) S += blocksum[b * 16 + jj] * expf(blockmax[b * 16 + jj] - M);
    *M_out = M;
    *rs_out = 1.0f / S;
}

// ---------------------------------------------------------------------------
// init: uf = query_vector    grid: B blocks, 256 threads
// ---------------------------------------------------------------------------
__global__ void init_kernel(const float* __restrict__ qv, float* __restrict__ uf) {
    int b = blockIdx.x, i = threadIdx.x;
    uf[(size_t)b * Ddim + i] = qv[(size_t)b * Ddim + i];
}

// ---------------------------------------------------------------------------
// dot: D[v*16+b] = tab[v,:].uf[b,:]  (GEMM microtile, round-6 verified)
//      + Hdot[b,j] = hist[b,j,:].uf[b,:]
// grid: DOT_TILES + HD_TILES = 881 blocks, 256 threads
// ---------------------------------------------------------------------------
__global__ void dot_kernel(const float* __restrict__ tab, const float* __restrict__ uf,
                           const float* __restrict__ hist,
                           float* __restrict__ D, float* __restrict__ Hdot) {
    int bid = blockIdx.x, tid = threadIdx.x;
    if (bid < DOT_TILES) {
        __shared__ __align__(16) float tl[DOT_VT][DOT_KC + 4];
        __shared__ __align__(16) float ufl[Bdim][DOT_KC + 4];
        int v0 = bid * DOT_VT;
        int vA = (tid >> 3) * 2, vB = vA + 1;
        int bA = (tid & 7) * 2,  bB = bA + 1;
        float aA0 = 0.f, aA1 = 0.f, aB0 = 0.f, aB1 = 0.f;
        for (int kc = 0; kc < Ddim; kc += DOT_KC) {
            __syncthreads();
#pragma unroll
            for (int i = 0; i < 4; ++i) {
                int idx = tid + i * 256;
                int r = idx >> 4, c4 = idx & 15;
                *(float4*)(&tl[r][c4 * 4]) =
                    *(const float4*)(tab + (size_t)(v0 + r) * Ddim + kc + c4 * 4);
            }
            {
                int r = tid >> 4, c4 = tid & 15;
                *(float4*)(&ufl[r][c4 * 4]) =
                    *(const float4*)(uf + (size_t)r * Ddim + kc + c4 * 4);
            }
            __syncthreads();
#pragma unroll
            for (int k4 = 0; k4 < DOT_KC / 4; ++k4) {
                const float4 a  = *(const float4*)(&tl[vA][k4 * 4]);
                const float4 c  = *(const float4*)(&tl[vB][k4 * 4]);
                const float4 u0 = *(const float4*)(&ufl[bA][k4 * 4]);
                const float4 u1 = *(const float4*)(&ufl[bB][k4 * 4]);
                aA0 += a.x*u0.x + a.y*u0.y + a.z*u0.z + a.w*u0.w;
                aA1 += a.x*u1.x + a.y*u1.y + a.z*u1.z + a.w*u1.w;
                aB0 += c.x*u0.x + c.y*u0.y + c.z*u0.z + c.w*u0.w;
                aB1 += c.x*u1.x + c.y*u1.y + c.z*u1.z + c.w*u1.w;
            }
        }
        size_t base = (size_t)(v0 + vA) * Bdim;
        D[base + bA] = aA0;  D[base + bB] = aA1;
        D[base + Bdim + bA] = aB0;  D[base + Bdim + bB] = aB1;
    } else {
        int r = bid - DOT_TILES;
        int b = r >> 4, j0 = (r & 15) * HD_JPB;
        int wave = tid >> 6, lane = tid & 63;
        const float4 u = *(const float4*)(uf + (size_t)b * Ddim + lane * 4);
        for (int j = j0 + wave; j < j0 + HD_JPB; j += 4) {
            const float4 h = *(const float4*)(hist + ((size_t)b * CONVMAX + j) * Ddim + lane * 4);
            float s = h.x*u.x + h.y*u.y + h.z*u.z + h.w*u.w;
#pragma unroll
            for (int off = 32; off > 0; off >>= 1) s += __shfl_xor(s, off, 64);
            if (lane == 0) Hdot[b * CONVMAX + j] = s;
        }
    }
}

// ---------------------------------------------------------------------------
// logit + per-block softmax partials (+ zero w/pwin in surplus blocks)
// grid: LG_TILES [+ ZW + PW] blocks, 256 threads
// ---------------------------------------------------------------------------
__global__ void logit_stats_kernel(const int* __restrict__ story, const int* __restrict__ kb_len,
                                   const int* __restrict__ conv_len, const float* __restrict__ D,
                                   const float* __restrict__ Hdot, const float* __restrict__ gp,
                                   float* __restrict__ lgbuf, float* __restrict__ blockmax,
                                   float* __restrict__ blocksum, float* __restrict__ w,
                                   float* __restrict__ pwin) {
    int bid = blockIdx.x, tid = threadIdx.x;
    if (bid >= LG_TILES) {
        int r = bid - LG_TILES;
        if (r < ZW_BLOCKS) {
            *(float4*)(w + (size_t)r * 1024 + tid * 4) = make_float4(0.f, 0.f, 0.f, 0.f);
        } else {
            *(float4*)(pwin + (size_t)(r - ZW_BLOCKS) * 1024 + tid * 4) = make_float4(0.f, 0.f, 0.f, 0.f);
        }
        return;
    }
    int row = bid * 256 + tid;
    int b = row >> 12, m = row & (Mdim - 1);
    const int4 st = *(const int4*)(story + (size_t)row * Tdim);
    float l = D[st.x*Bdim + b] + D[st.y*Bdim + b] + D[st.z*Bdim + b] + D[st.w*Bdim + b];
    unsigned j = (unsigned)(m - kb_len[b]);
    if (j < (unsigned)conv_len[b]) l += Hdot[b * CONVMAX + j];
    l *= gp[row];
    lgbuf[row] = l;
    __shared__ float sh[256];
    sh[tid] = l; __syncthreads();
    for (int s = 128; s > 0; s >>= 1) { if (tid < s) sh[tid] = fmaxf(sh[tid], sh[tid + s]); __syncthreads(); }
    float bm = sh[0]; __syncthreads();
    sh[tid] = expf(l - bm); __syncthreads();
    for (int s = 128; s > 0; s >>= 1) { if (tid < s) sh[tid] += sh[tid + s]; __syncthreads(); }
    if (tid == 0) { blockmax[bid] = bm; blocksum[bid] = sh[0]; }
}

// ---------------------------------------------------------------------------
// scatter: p = softmax(l)*gp; w[st[t],b] += p (x4 atomics over 640K addrs);
//          pwin for the history window.   grid: LG_TILES blocks, 256 threads
// ---------------------------------------------------------------------------
__global__ void scatter_kernel(const int* __restrict__ story, const int* __restrict__ kb_len,
                               const int* __restrict__ conv_len, const float* __restrict__ logits,
                               const float* __restrict__ blockmax, const float* __restrict__ blocksum,
                               const float* __restrict__ gp, float* __restrict__ w,
                               float* __restrict__ pwin) {
    int bid = blockIdx.x, tid = threadIdx.x;
    int b = bid >> 4;
    float M, rs;
    combine_stats(blockmax, blocksum, b, &M, &rs);
    int row = bid * 256 + tid;
    int m = row & (Mdim - 1);
    float p = expf(logits[row] - M) * rs * gp[row];
    const int4 st = *(const int4*)(story + (size_t)row * Tdim);
    atomicAdd(&w[st.x * Bdim + b], p);
    atomicAdd(&w[st.y * Bdim + b], p);
    atomicAdd(&w[st.z * Bdim + b], p);
    atomicAdd(&w[st.w * Bdim + b], p);
    unsigned j = (unsigned)(m - kb_len[b]);
    if (j < (unsigned)conv_len[b]) pwin[b * CONVMAX + j] = p;
}

// ---------------------------------------------------------------------------
// wsum: partial[b][tile][:] = sum_{v in tile} w[v,b]*tab[v,:]  (no atomics)
//       + histpart[b][c][:] over 64-j hist chunks
// grid: WS_TILES + WH_TILES = 928 blocks, 256 threads
// ---------------------------------------------------------------------------
__global__ void wsum_kernel(const float* __restrict__ tab, const float* __restrict__ w,
                            const float* __restrict__ pwin, const float* __restrict__ hist,
                            float* __restrict__ partial, float* __restrict__ histpart) {
    int bid = blockIdx.x, tid = threadIdx.x;
    if (bid < WS_TILES) {
        __shared__ float wsl[WS_VT * Bdim];
        int v0 = bid * WS_VT;
        for (int i = tid; i < WS_VT * Bdim; i += 256) wsl[i] = w[(size_t)v0 * Bdim + i];
        __syncthreads();
        int wave = tid >> 6, lane = tid & 63;
        int b0 = wave * 4, d4 = lane * 4;
        float4 a0 = make_float4(0.f,0.f,0.f,0.f), a1 = a0, a2 = a0, a3 = a0;
        for (int v = 0; v < WS_VT; ++v) {
            const float4 t = *(const float4*)(tab + (size_t)(v0 + v) * Ddim + d4);
            float w0 = wsl[v*Bdim + b0],   w1 = wsl[v*Bdim + b0+1];
            float w2 = wsl[v*Bdim + b0+2], w3 = wsl[v*Bdim + b0+3];
            a0.x += w0*t.x; a0.y += w0*t.y; a0.z += w0*t.z; a0.w += w0*t.w;
            a1.x += w1*t.x; a1.y += w1*t.y; a1.z += w1*t.z; a1.w += w1*t.w;
            a2.x += w2*t.x; a2.y += w2*t.y; a2.z += w2*t.z; a2.w += w2*t.w;
            a3.x += w3*t.x; a3.y += w3*t.y; a3.z += w3*t.z; a3.w += w3*t.w;
        }
        *(float4*)(&partial[((size_t)(b0+0) * WS_TILES + bid) * Ddim + d4]) = a0;
        *(float4*)(&partial[((size_t)(b0+1) * WS_TILES + bid) * Ddim + d4]) = a1;
        *(float4*)(&partial[((size_t)(b0+2) * WS_TILES + bid) * Ddim + d4]) = a2;
        *(float4*)(&partial[((size_t)(b0+3) * WS_TILES + bid) * Ddim + d4]) = a3;
    } else {
        int r = bid - WS_TILES;
        int b = r >> 3, c = r & 7, j0 = c * WH_JPB;
        __shared__ float sp[WH_JPB];
        if (tid < WH_JPB) sp[tid] = pwin[b * CONVMAX + j0 + tid];
        __syncthreads();
        float acc = 0.f;
        const float* hb = hist + ((size_t)b * CONVMAX + j0) * Ddim + tid;
#pragma unroll 8
        for (int j = 0; j < WH_JPB; ++j) acc += sp[j] * hb[(size_t)j * Ddim];
        histpart[((size_t)b * UF_CH + c) * Ddim + tid] = acc;
    }
}

// ---------------------------------------------------------------------------
// ufred: uf[b,:] += chunk-sums of partial + histpart   (atomic, uncontended)
// grid: Bdim * UF_CH = 128 blocks, 256 threads
// ---------------------------------------------------------------------------
__global__ void ufred_kernel(const float* __restrict__ partial, const float* __restrict__ histpart,
                             float* __restrict__ uf) {
    int b = blockIdx.x >> 3, c = blockIdx.x & 7;
    int tid = threadIdx.x;
    float acc = 0.f;
    const float* base = partial + ((size_t)b * WS_TILES + c * UF_PER) * Ddim + tid;
#pragma unroll 4
    for (int i = 0; i < UF_PER; ++i) acc += base[(size_t)i * Ddim];
    acc += histpart[((size_t)b * UF_CH + c) * Ddim + tid];
    atomicAdd(&uf[(size_t)b * Ddim + tid], acc);
}

// ---------------------------------------------------------------------------
// att: final hop — recompute e3(row) by gather; prob = softmax*gp;
//      attpart[b][ch] = sum_m prob*e3; e3 -> out_m (NT); psoft (NT).
// grid: ATT_TILES = 2048 blocks, 256 threads (wave per row)
// ---------------------------------------------------------------------------
__global__ void att_kernel(const int* __restrict__ story, const int* __restrict__ kb_len,
                           const int* __restrict__ conv_len, const float* __restrict__ hist,
                           const float* __restrict__ tab, const float* __restrict__ logits,
                           const float* __restrict__ blockmax, const float* __restrict__ blocksum,
                           const float* __restrict__ gp,
                           float* __restrict__ attpart, float* __restrict__ out_m,
                           float* __restrict__ out_psoft) {
    int bid = blockIdx.x;
    int b  = bid >> 7;                   // / ATT_CH
    int m0 = (bid & (ATT_CH - 1)) * MT;
    int tid = threadIdx.x, wave = tid >> 6, lane = tid & 63;
    int d4 = lane * 4;
    __shared__ float prob[MT];
    __shared__ float4 red[4][64];
    if (tid < MT) {
        float M, rs;
        combine_stats(blockmax, blocksum, b, &M, &rs);
        size_t row = (size_t)b * Mdim + m0 + tid;
        float pn = expf(logits[row] - M) * rs;
        nt_store1(out_psoft + row, pn);
        prob[tid] = pn * gp[row];
    }
    __syncthreads();
    int kb = kb_len[b], cl = conv_len[b];
    float4 acc = make_float4(0.f, 0.f, 0.f, 0.f);
#pragma unroll 2
    for (int mm = wave; mm < MT; mm += 4) {
        int m = m0 + mm;
        size_t row = (size_t)b * Mdim + m;
        const int* st = story + row * Tdim;
        float4 v = make_float4(0.f, 0.f, 0.f, 0.f);
#pragma unroll
        for (int t = 0; t < Tdim; ++t) {
            const float4 wv = *(const float4*)(tab + (size_t)st[t] * Ddim + d4);
            v.x += wv.x; v.y += wv.y; v.z += wv.z; v.w += wv.w;
        }
        if (m >= kb && m < kb + cl) {
            const float4 h = *(const float4*)(hist + ((size_t)b * CONVMAX + (m - kb)) * Ddim + d4);
            v.x += h.x; v.y += h.y; v.z += h.z; v.w += h.w;
        }
        nt_store4(out_m + row * Ddim + d4, v);
        float p = prob[mm];
        acc.x += p * v.x; acc.y += p * v.y; acc.z += p * v.z; acc.w += p * v.w;
    }
    red[wave][lane] = acc;
    __syncthreads();
    if (wave == 0) {
        float4 a0 = red[0][lane], a1 = red[1][lane], a2 = red[2][lane], a3 = red[3][lane];
        float4 t4;
        t4.x = a0.x + a1.x + a2.x + a3.x;
        t4.y = a0.y + a1.y + a2.y + a3.y;
        t4.z = a0.z + a1.z + a2.z + a3.z;
        t4.w = a0.w + a1.w + a2.w + a3.w;
        *(float4*)(&attpart[((size_t)b * ATT_CH + (bid & (ATT_CH - 1))) * Ddim + d4]) = t4;
    }
}

// ---------------------------------------------------------------------------
// attred: uf[b,:] += chunk-sums of attpart   grid: Bdim*4 = 64 blocks
// ---------------------------------------------------------------------------
__global__ void attred_kernel(const float* __restrict__ attpart, float* __restrict__ uf) {
    int b = blockIdx.x >> 2, c = blockIdx.x & 3;
    int tid = threadIdx.x;
    float acc = 0.f;
    const float* base = attpart + ((size_t)b * ATT_CH + c * 32) * Ddim + tid;
#pragma unroll 4
    for (int i = 0; i < 32; ++i) acc += base[(size_t)i * Ddim];
    atomicAdd(&uf[(size_t)b * Ddim + tid], acc);
}

extern "C" void kernel_launch(void* const* d_in, const int* in_sizes, int n_in,
                              void* d_out, int out_size, void* d_ws, size_t ws_size,
                              hipStream_t stream) {
    const int*   story        = (const int*)d_in[0];
    const int*   kb_len       = (const int*)d_in[1];
    const int*   conv_len     = (const int*)d_in[2];
    // d_in[3] (query), d_in[8..11] (Tg_w, Tg_b, FW_w, FW_b): dead w.r.t. outputs
    const float* hist         = (const float*)d_in[4];
    const float* query_vector = (const float*)d_in[5];
    const float* gp           = (const float*)d_in[6];
    const float* C_emb        = (const float*)d_in[7];

    float* out        = (float*)d_out;
    float* out_psoft  = out;                                   // B*M
    float* out_logits = out + (size_t)Bdim * Mdim;             // B*M
    float* out_uf     = out + 2 * (size_t)Bdim * Mdim;         // B*D
    float* out_m      = out + 2 * (size_t)Bdim * Mdim + (size_t)Bdim * Ddim; // B*M*D

    float* wsp = (float*)d_ws;
    float* D        = wsp;                                     // V*B
    float* w        = D + (size_t)Vdim * Bdim;                 // V*B
    float* Hdot     = w + (size_t)Vdim * Bdim;                 // B*CONVMAX
    float* pwin     = Hdot + (size_t)Bdim * CONVMAX;           // B*CONVMAX
    float* logits   = pwin + (size_t)Bdim * CONVMAX;           // B*M
    float* blockmax = logits + (size_t)Bdim * Mdim;            // 256
    float* blocksum = blockmax + 256;                          // 256
    float* partial  = blocksum + 256;                          // B*800*D
    float* histpart = partial + (size_t)Bdim * WS_TILES * Ddim; // B*8*D
    float* attpart  = histpart + (size_t)Bdim * UF_CH * Ddim;  // B*128*D

    const size_t TAB = (size_t)Vdim * Ddim;
    const float* tab[4] = { C_emb, C_emb + TAB, C_emb + 2*TAB, C_emb + 3*TAB };

    init_kernel<<<Bdim, Ddim, 0, stream>>>(query_vector, out_uf);

    for (int h = 0; h < 2; ++h) {
        const float* ufsrc = (h == 0) ? query_vector : out_uf;
        dot_kernel<<<DOT_TILES + HD_TILES, 256, 0, stream>>>(tab[h], ufsrc, hist, D, Hdot);
        logit_stats_kernel<<<LG_TILES + ZW_BLOCKS + PW_BLOCKS, 256, 0, stream>>>(
            story, kb_len, conv_len, D, Hdot, gp, logits, blockmax, blocksum, w, pwin);
        scatter_kernel<<<LG_TILES, 256, 0, stream>>>(story, kb_len, conv_len, logits,
                                                     blockmax, blocksum, gp, w, pwin);
        wsum_kernel<<<WS_TILES + WH_TILES, 256, 0, stream>>>(tab[h + 1], w, pwin, hist,
                                                             partial, histpart);
        ufred_kernel<<<Bdim * UF_CH, 256, 0, stream>>>(partial, histpart, out_uf);
    }

    // hop 2: logits/psoft are outputs; out_m forces the one real gather pass
    dot_kernel<<<DOT_TILES + HD_TILES, 256, 0, stream>>>(tab[2], out_uf, hist, D, Hdot);
    logit_stats_kernel<<<LG_TILES, 256, 0, stream>>>(
        story, kb_len, conv_len, D, Hdot, gp, out_logits, blockmax, blocksum, nullptr, nullptr);
    att_kernel<<<ATT_TILES, 256, 0, stream>>>(story, kb_len, conv_len, hist, tab[3],
                                              out_logits, blockmax, blocksum, gp,
                                              attpart, out_m, out_psoft);
    attred_kernel<<<Bdim * 4, 256, 0, stream>>>(attpart, out_uf);
}